// Round 1
// baseline (41803.510 us; speedup 1.0000x reference)
//
#include <hip/hip_runtime.h>
#include <math.h>

#define AGENT __HIP_MEMORY_SCOPE_AGENT

__device__ __forceinline__ float sigf(float x) { return 1.f / (1.f + __expf(-x)); }
__device__ __forceinline__ float lrelu(float x) { return x > 0.f ? x : 0.01f * x; }
__device__ __forceinline__ float aload(const float* p) {
    return __hip_atomic_load(p, __ATOMIC_RELAXED, AGENT);
}
__device__ __forceinline__ void astore(float* p, float v) {
    __hip_atomic_store(p, v, __ATOMIC_RELAXED, AGENT);
}

// ---------------- generic fp32 GEMM: C[m][n] = sum_k A[m][k]*B[n][k] + bias ----
template <bool LRELU>
__global__ __launch_bounds__(256) void gemm_bias(
    const float* __restrict__ A, const float* __restrict__ B,
    const float* __restrict__ bias1, const float* __restrict__ bias2,
    float* __restrict__ C, int M, int N, int K)
{
    __shared__ float As[16][68];
    __shared__ float Bs[16][68];
    const int tid = threadIdx.x;
    const int m0 = blockIdx.y * 64, n0 = blockIdx.x * 64;
    const int tm = tid >> 4, tn = tid & 15;
    const int lr = tid >> 2;          // 0..63 tile row
    const int lk = (tid & 3) * 4;     // 0,4,8,12
    float acc[4][4] = {};
    for (int k0 = 0; k0 < K; k0 += 16) {
        float4 av = make_float4(0.f, 0.f, 0.f, 0.f);
        if (m0 + lr < M) av = *(const float4*)&A[(size_t)(m0 + lr) * K + k0 + lk];
        As[lk + 0][lr] = av.x; As[lk + 1][lr] = av.y;
        As[lk + 2][lr] = av.z; As[lk + 3][lr] = av.w;
        float4 bv = make_float4(0.f, 0.f, 0.f, 0.f);
        if (n0 + lr < N) bv = *(const float4*)&B[(size_t)(n0 + lr) * K + k0 + lk];
        Bs[lk + 0][lr] = bv.x; Bs[lk + 1][lr] = bv.y;
        Bs[lk + 2][lr] = bv.z; Bs[lk + 3][lr] = bv.w;
        __syncthreads();
#pragma unroll
        for (int kk = 0; kk < 16; kk++) {
            float a[4], b[4];
#pragma unroll
            for (int i = 0; i < 4; i++) a[i] = As[kk][tm * 4 + i];
#pragma unroll
            for (int j = 0; j < 4; j++) b[j] = Bs[kk][tn * 4 + j];
#pragma unroll
            for (int i = 0; i < 4; i++)
#pragma unroll
                for (int j = 0; j < 4; j++) acc[i][j] += a[i] * b[j];
        }
        __syncthreads();
    }
#pragma unroll
    for (int i = 0; i < 4; i++) {
#pragma unroll
        for (int j = 0; j < 4; j++) {
            int mm = m0 + tm * 4 + i, nn = n0 + tn * 4 + j;
            if (mm < M && nn < N) {
                float v = acc[i][j];
                if (bias1) v += bias1[nn];
                if (bias2) v += bias2[nn];
                if (LRELU) v = lrelu(v);
                C[(size_t)mm * N + nn] = v;
            }
        }
    }
}

// ---------------- persistent pipelined LSTM1+LSTM2 scan ------------------------
// WGs 0..63  : LSTM1 (H=512). WG wg owns h indices [wg*8, wg*8+8); 32 GEMV rows
//              of W_hh1 held in registers (64 floats / thread).
// WGs 64..95 : LSTM2 (H=256), pipelined 1 step behind; computes its own input
//              projection from h1seq on the fly (W_ih2 + W_hh2 rows in regs).
__global__ __launch_bounds__(256) void lstm_pipe(
    const float* __restrict__ gx1, const float* __restrict__ Whh1,
    const float* __restrict__ Wih2, const float* __restrict__ Whh2,
    const float* __restrict__ bih2, const float* __restrict__ bhh2,
    float* __restrict__ h1seq, float* __restrict__ h2seq,
    float* __restrict__ h1buf, float* __restrict__ h2buf,
    int* __restrict__ cnt1, int* __restrict__ cnt2)
{
    const int wg = blockIdx.x, tid = threadIdx.x;
    const int r = tid & 31, p = tid >> 5;
    __shared__ float xl[512];
    __shared__ float hl[256];
    __shared__ float part[8][32];
    __shared__ float gxl[32];
    __shared__ float gsum[32];
    __shared__ float cst[8];
    if (tid < 8) cst[tid] = 0.f;
    __syncthreads();

    if (wg < 64) {
        const int jb = wg * 8;
        const int grow = (r >> 3) * 512 + jb + (r & 7);
        float w[64];
#pragma unroll
        for (int q = 0; q < 64; q++) w[q] = Whh1[(size_t)grow * 512 + p * 64 + q];
        for (int t = 0; t < 4096; ++t) {
            if (t > 0 && tid == 0)
                while (__hip_atomic_load(&cnt1[t - 1], __ATOMIC_ACQUIRE, AGENT) < 64) {}
            __syncthreads();
            if (t == 0) { xl[tid] = 0.f; xl[tid + 256] = 0.f; }
            else {
                const float* hp = h1buf + ((t - 1) & 1) * 512;
                xl[tid] = aload(hp + tid);
                xl[tid + 256] = aload(hp + tid + 256);
            }
            if (tid < 32) gxl[tid] = gx1[(size_t)t * 2048 + (tid >> 3) * 512 + jb + (tid & 7)];
            __syncthreads();
            float acc = 0.f;
#pragma unroll
            for (int q = 0; q < 64; q++) acc += w[q] * xl[p * 64 + q];
            part[p][r] = acc;
            __syncthreads();
            if (tid < 32) {
                float s = gxl[tid];
#pragma unroll
                for (int pp = 0; pp < 8; pp++) s += part[pp][tid];
                gsum[tid] = s;
            }
            __syncthreads();
            if (tid < 8) {
                float ig = sigf(gsum[tid]);
                float fg = sigf(gsum[8 + tid]);
                float gg = tanhf(gsum[16 + tid]);
                float og = sigf(gsum[24 + tid]);
                float c = fg * cst[tid] + ig * gg;
                cst[tid] = c;
                float h = og * tanhf(c);
                astore(h1buf + (t & 1) * 512 + jb + tid, h);
                astore(h1seq + (size_t)t * 512 + jb + tid, lrelu(h));
            }
            __syncthreads();
            __threadfence();
            if (tid == 0) __hip_atomic_fetch_add(&cnt1[t], 1, __ATOMIC_RELEASE, AGENT);
        }
    } else {
        const int k = wg - 64, jb = k * 8;
        const int grow = (r >> 3) * 256 + jb + (r & 7);
        float wi[64], wh[32];
#pragma unroll
        for (int q = 0; q < 64; q++) wi[q] = Wih2[(size_t)grow * 512 + p * 64 + q];
#pragma unroll
        for (int q = 0; q < 32; q++) wh[q] = Whh2[(size_t)grow * 256 + p * 32 + q];
        const float biasr = (tid < 32) ? (bih2[grow] + bhh2[grow]) : 0.f;
        for (int t = 0; t < 4096; ++t) {
            if (tid == 0)
                while (__hip_atomic_load(&cnt1[t], __ATOMIC_ACQUIRE, AGENT) < 64) {}
            if (t > 0 && tid == 1)
                while (__hip_atomic_load(&cnt2[t - 1], __ATOMIC_ACQUIRE, AGENT) < 32) {}
            __syncthreads();
            {
                const float* xp = h1seq + (size_t)t * 512;
                xl[tid] = aload(xp + tid);
                xl[tid + 256] = aload(xp + tid + 256);
            }
            hl[tid] = (t == 0) ? 0.f : aload(h2buf + ((t - 1) & 1) * 256 + tid);
            __syncthreads();
            float acc = 0.f;
#pragma unroll
            for (int q = 0; q < 64; q++) acc += wi[q] * xl[p * 64 + q];
#pragma unroll
            for (int q = 0; q < 32; q++) acc += wh[q] * hl[p * 32 + q];
            part[p][r] = acc;
            __syncthreads();
            if (tid < 32) {
                float s = biasr;
#pragma unroll
                for (int pp = 0; pp < 8; pp++) s += part[pp][tid];
                gsum[tid] = s;
            }
            __syncthreads();
            if (tid < 8) {
                float ig = sigf(gsum[tid]);
                float fg = sigf(gsum[8 + tid]);
                float gg = tanhf(gsum[16 + tid]);
                float og = sigf(gsum[24 + tid]);
                float c = fg * cst[tid] + ig * gg;
                cst[tid] = c;
                float h = og * tanhf(c);
                astore(h2buf + (t & 1) * 256 + jb + tid, h);
                h2seq[(size_t)t * 256 + jb + tid] = lrelu(h);
            }
            __syncthreads();
            __threadfence();
            if (tid == 0) __hip_atomic_fetch_add(&cnt2[t], 1, __ATOMIC_RELEASE, AGENT);
        }
    }
}

// ---------------- GCN edge scatter: y[dst] += ew * m[src] ----------------------
__global__ void gcn_scatter(const float* __restrict__ m, const int* __restrict__ ei,
                            const float* __restrict__ ew, float* __restrict__ y,
                            int shift, int nE)
{
    int idx = blockIdx.x * 256 + threadIdx.x;
    int e = idx >> shift;
    if (e >= nE) return;
    int C = 1 << shift;
    int ch = idx & (C - 1);
    int s = ei[e], d = ei[nE + e];
    atomicAdd(&y[(size_t)d * C + ch], ew[e] * m[(size_t)s * C + ch]);
}

// ---------------- BN (training-mode batch stats) -------------------------------
__global__ __launch_bounds__(256) void bn_stats(
    const float* __restrict__ x, const float* __restrict__ gamma,
    const float* __restrict__ beta, float* __restrict__ scale,
    float* __restrict__ shift, int Nn, int C)
{
    int ch = blockIdx.x;
    float s = 0.f, s2 = 0.f;
    for (int n = threadIdx.x; n < Nn; n += 256) {
        float v = x[(size_t)n * C + ch];
        s += v; s2 += v * v;
    }
    __shared__ float rs[256], rq[256];
    rs[threadIdx.x] = s; rq[threadIdx.x] = s2;
    __syncthreads();
    for (int o = 128; o > 0; o >>= 1) {
        if (threadIdx.x < o) {
            rs[threadIdx.x] += rs[threadIdx.x + o];
            rq[threadIdx.x] += rq[threadIdx.x + o];
        }
        __syncthreads();
    }
    if (threadIdx.x == 0) {
        float mean = rs[0] / Nn;
        float var = rq[0] / Nn - mean * mean;
        float inv = rsqrtf(var + 1e-5f);
        float sc = gamma[ch] * inv;
        scale[ch] = sc;
        shift[ch] = beta[ch] - mean * sc;
    }
}

__global__ void bn_apply(const float* __restrict__ x, const float* __restrict__ scale,
                         const float* __restrict__ shift, float* __restrict__ z,
                         int mask, int total)
{
    int idx = blockIdx.x * 256 + threadIdx.x;
    if (idx >= total) return;
    int ch = idx & mask;
    z[idx] = lrelu(x[idx] * scale[ch] + shift[ch]);
}

// ---------------- global_add_pool via batch array ------------------------------
__global__ void pool_kernel(const float* __restrict__ z, const int* __restrict__ batch,
                            float* __restrict__ pooled, int total)
{
    int idx = blockIdx.x * 256 + threadIdx.x;
    if (idx >= total) return;
    int n = idx >> 5, ch = idx & 31;
    atomicAdd(&pooled[(size_t)batch[n] * 32 + ch], z[idx]);
}

// ---------------- final tiny MLP: 32 -> 16 -> 8 -> 2, one thread per graph -----
__global__ void mlp_kernel(const float* __restrict__ pooled,
                           const float* __restrict__ w2, const float* __restrict__ b2,
                           const float* __restrict__ w3, const float* __restrict__ b3,
                           const float* __restrict__ w4, const float* __restrict__ b4,
                           float* __restrict__ out)
{
    int g = blockIdx.x * 256 + threadIdx.x;
    if (g >= 512) return;
    float pbuf[32];
#pragma unroll
    for (int i = 0; i < 32; i++) pbuf[i] = pooled[g * 32 + i];
    float a[16];
#pragma unroll
    for (int j = 0; j < 16; j++) {
        float s = b2[j];
#pragma unroll
        for (int i = 0; i < 32; i++) s += w2[j * 32 + i] * pbuf[i];
        a[j] = lrelu(s);
    }
    float c8[8];
#pragma unroll
    for (int j = 0; j < 8; j++) {
        float s = b3[j];
#pragma unroll
        for (int i = 0; i < 16; i++) s += w3[j * 16 + i] * a[i];
        c8[j] = lrelu(s);
    }
#pragma unroll
    for (int j = 0; j < 2; j++) {
        float s = b4[j];
#pragma unroll
        for (int i = 0; i < 8; i++) s += w4[j * 8 + i] * c8[i];
        out[g * 2 + j] = lrelu(s);
    }
}

extern "C" void kernel_launch(void* const* d_in, const int* in_sizes, int n_in,
                              void* d_out, int out_size, void* d_ws, size_t ws_size,
                              hipStream_t stream)
{
    (void)in_sizes; (void)n_in; (void)out_size; (void)ws_size;
    const float* x      = (const float*)d_in[0];
    const int*   ei     = (const int*)d_in[1];
    const float* ew     = (const float*)d_in[2];
    const int*   batch  = (const int*)d_in[3];
    const float* W_ih1  = (const float*)d_in[4];
    const float* W_hh1  = (const float*)d_in[5];
    const float* b_ih1  = (const float*)d_in[6];
    const float* b_hh1  = (const float*)d_in[7];
    const float* W_ih2  = (const float*)d_in[8];
    const float* W_hh2  = (const float*)d_in[9];
    const float* b_ih2  = (const float*)d_in[10];
    const float* b_hh2  = (const float*)d_in[11];
    const float* fc1_w  = (const float*)d_in[12];
    const float* fc1_b  = (const float*)d_in[13];
    const float* gcn1_w = (const float*)d_in[14];
    const float* bn1_g  = (const float*)d_in[16];
    const float* bn1_b  = (const float*)d_in[17];
    const float* gcn2_w = (const float*)d_in[18];
    const float* bn2_g  = (const float*)d_in[20];
    const float* bn2_b  = (const float*)d_in[21];
    const float* fc2_w  = (const float*)d_in[22];
    const float* fc2_b  = (const float*)d_in[23];
    const float* fc3_w  = (const float*)d_in[24];
    const float* fc3_b  = (const float*)d_in[25];
    const float* fc4_w  = (const float*)d_in[26];
    const float* fc4_b  = (const float*)d_in[27];
    float* out = (float*)d_out;

    // workspace layout (fp32 elements)
    float* ws    = (float*)d_ws;
    float* gx1   = ws;                       // 4096*2048
    float* h1seq = gx1   + 4096 * 2048;      // 4096*512
    float* h2seq = h1seq + 4096 * 512;       // 4096*256
    float* h3    = h2seq + 4096 * 256;       // 4096*128
    float* m1    = h3    + 4096 * 128;       // 4096*64
    float* y1    = m1    + 4096 * 64;        // 4096*64
    float* z1    = y1    + 4096 * 64;        // 4096*64
    float* m2    = z1    + 4096 * 64;        // 4096*32
    float* y2    = m2    + 4096 * 32;        // 4096*32
    float* z2    = y2    + 4096 * 32;        // 4096*32
    float* pooled = z2   + 4096 * 32;        // 512*32
    float* h1buf = pooled + 512 * 32;        // 2*512
    float* h2buf = h1buf + 2 * 512;          // 2*256
    float* scale1 = h2buf + 2 * 256;         // 64
    float* shift1 = scale1 + 64;             // 64
    float* scale2 = shift1 + 64;             // 32
    float* shift2 = scale2 + 32;             // 32
    int*   cnt1  = (int*)(shift2 + 32);      // 4096
    int*   cnt2  = cnt1 + 4096;              // 4096

    hipMemsetAsync(cnt1, 0, 2 * 4096 * sizeof(int), stream);
    hipMemsetAsync(y1, 0, 4096 * 64 * sizeof(float), stream);
    hipMemsetAsync(y2, 0, 4096 * 32 * sizeof(float), stream);
    hipMemsetAsync(pooled, 0, 512 * 32 * sizeof(float), stream);

    dim3 b256(256);

    // gx1 = x @ W_ih1^T + (b_ih1 + b_hh1)   [4096,2048]
    gemm_bias<false><<<dim3(2048 / 64, 4096 / 64), b256, 0, stream>>>(
        x, W_ih1, b_ih1, b_hh1, gx1, 4096, 2048, 1280);

    // both LSTM scans, pipelined
    lstm_pipe<<<96, b256, 0, stream>>>(gx1, W_hh1, W_ih2, W_hh2, b_ih2, b_hh2,
                                       h1seq, h2seq, h1buf, h2buf, cnt1, cnt2);

    // fc1 + lrelu  [4096,128]
    gemm_bias<true><<<dim3(128 / 64, 4096 / 64), b256, 0, stream>>>(
        h2seq, fc1_w, fc1_b, nullptr, h3, 4096, 128, 256);

    // gcn1 linear [4096,64]  (bias cancels in BN)
    gemm_bias<false><<<dim3(1, 4096 / 64), b256, 0, stream>>>(
        h3, gcn1_w, nullptr, nullptr, m1, 4096, 64, 128);
    gcn_scatter<<<(32768 * 64) / 256, b256, 0, stream>>>(m1, ei, ew, y1, 6, 32768);
    bn_stats<<<64, b256, 0, stream>>>(y1, bn1_g, bn1_b, scale1, shift1, 4096, 64);
    bn_apply<<<(4096 * 64) / 256, b256, 0, stream>>>(y1, scale1, shift1, z1, 63, 4096 * 64);

    // gcn2 linear [4096,32]
    gemm_bias<false><<<dim3(1, 4096 / 64), b256, 0, stream>>>(
        z1, gcn2_w, nullptr, nullptr, m2, 4096, 32, 64);
    gcn_scatter<<<(32768 * 32) / 256, b256, 0, stream>>>(m2, ei, ew, y2, 5, 32768);
    bn_stats<<<32, b256, 0, stream>>>(y2, bn2_g, bn2_b, scale2, shift2, 4096, 32);
    bn_apply<<<(4096 * 32) / 256, b256, 0, stream>>>(y2, scale2, shift2, z2, 31, 4096 * 32);

    // pool + MLP head
    pool_kernel<<<(4096 * 32) / 256, b256, 0, stream>>>(z2, batch, pooled, 4096 * 32);
    mlp_kernel<<<2, b256, 0, stream>>>(pooled, fc2_w, fc2_b, fc3_w, fc3_b,
                                       fc4_w, fc4_b, out);
}

// Round 2
// 14145.389 us; speedup vs baseline: 2.9553x; 2.9553x over previous
//
#include <hip/hip_runtime.h>
#include <math.h>

#define AGENT __HIP_MEMORY_SCOPE_AGENT

__device__ __forceinline__ float sigf(float x) { return 1.f / (1.f + __expf(-x)); }
__device__ __forceinline__ float lrelu(float x) { return x > 0.f ? x : 0.01f * x; }
__device__ __forceinline__ float aload(const float* p) {
    return __hip_atomic_load(p, __ATOMIC_RELAXED, AGENT);
}
__device__ __forceinline__ void astore(float* p, float v) {
    __hip_atomic_store(p, v, __ATOMIC_RELAXED, AGENT);
}
__device__ __forceinline__ int aloadi(const int* p) {
    return __hip_atomic_load(p, __ATOMIC_RELAXED, AGENT);
}
__device__ __forceinline__ void astorei(int* p, int v) {
    __hip_atomic_store(p, v, __ATOMIC_RELAXED, AGENT);
}

// ---------------- generic fp32 GEMM: C[m][n] = sum_k A[m][k]*B[n][k] + bias ----
template <bool LRELU>
__global__ __launch_bounds__(256) void gemm_bias(
    const float* __restrict__ A, const float* __restrict__ B,
    const float* __restrict__ bias1, const float* __restrict__ bias2,
    float* __restrict__ C, int M, int N, int K)
{
    __shared__ float As[16][68];
    __shared__ float Bs[16][68];
    const int tid = threadIdx.x;
    const int m0 = blockIdx.y * 64, n0 = blockIdx.x * 64;
    const int tm = tid >> 4, tn = tid & 15;
    const int lr = tid >> 2;          // 0..63 tile row
    const int lk = (tid & 3) * 4;     // 0,4,8,12
    float acc[4][4] = {};
    for (int k0 = 0; k0 < K; k0 += 16) {
        float4 av = make_float4(0.f, 0.f, 0.f, 0.f);
        if (m0 + lr < M) av = *(const float4*)&A[(size_t)(m0 + lr) * K + k0 + lk];
        As[lk + 0][lr] = av.x; As[lk + 1][lr] = av.y;
        As[lk + 2][lr] = av.z; As[lk + 3][lr] = av.w;
        float4 bv = make_float4(0.f, 0.f, 0.f, 0.f);
        if (n0 + lr < N) bv = *(const float4*)&B[(size_t)(n0 + lr) * K + k0 + lk];
        Bs[lk + 0][lr] = bv.x; Bs[lk + 1][lr] = bv.y;
        Bs[lk + 2][lr] = bv.z; Bs[lk + 3][lr] = bv.w;
        __syncthreads();
#pragma unroll
        for (int kk = 0; kk < 16; kk++) {
            float a[4], b[4];
#pragma unroll
            for (int i = 0; i < 4; i++) a[i] = As[kk][tm * 4 + i];
#pragma unroll
            for (int j = 0; j < 4; j++) b[j] = Bs[kk][tn * 4 + j];
#pragma unroll
            for (int i = 0; i < 4; i++)
#pragma unroll
                for (int j = 0; j < 4; j++) acc[i][j] += a[i] * b[j];
        }
        __syncthreads();
    }
#pragma unroll
    for (int i = 0; i < 4; i++) {
#pragma unroll
        for (int j = 0; j < 4; j++) {
            int mm = m0 + tm * 4 + i, nn = n0 + tn * 4 + j;
            if (mm < M && nn < N) {
                float v = acc[i][j];
                if (bias1) v += bias1[nn];
                if (bias2) v += bias2[nn];
                if (LRELU) v = lrelu(v);
                C[(size_t)mm * N + nn] = v;
            }
        }
    }
}

// ---------------- persistent pipelined LSTM1+LSTM2 scan ------------------------
// Fence-free signaling: data via write-through agent atomics, drained by the
// vmcnt(0) inside __syncthreads / explicit s_waitcnt; publication via relaxed
// per-WG flag stores (distinct addresses); consumers poll 64 flags with wave 0
// lanes + __all (no acquire, no RMW, no threadfence).
__global__ __launch_bounds__(256) void lstm_pipe(
    const float* __restrict__ gx1, const float* __restrict__ Whh1,
    const float* __restrict__ Wih2, const float* __restrict__ Whh2,
    const float* __restrict__ bih2, const float* __restrict__ bhh2,
    float* __restrict__ h1seq, float* __restrict__ h2seq,
    float* __restrict__ h1buf, float* __restrict__ h2buf,
    int* __restrict__ flag1, int* __restrict__ flag2)
{
    const int wg = blockIdx.x, tid = threadIdx.x;
    const int r = tid & 31, p = tid >> 5;
    __shared__ float xl[512];
    __shared__ float hl[256];
    __shared__ float part[8][32];
    __shared__ float gxl[32];

    if (wg < 64) {
        // ---------------- LSTM1: H=512, owns h[jb..jb+8) ----------------
        const int jb = wg * 8;
        const int grow = (r >> 3) * 512 + jb + (r & 7);
        float w[64];
#pragma unroll
        for (int q = 0; q < 64; q++) w[q] = Whh1[(size_t)grow * 512 + p * 64 + q];
        float cstate = 0.f;  // element tid (only tid<8 uses)

        for (int t = 0; t < 4096; ++t) {
            // prefetch gx for this step (independent of the flag wait)
            float gxv = 0.f;
            if (tid < 32) gxv = gx1[(size_t)t * 2048 + (tid >> 3) * 512 + jb + (tid & 7)];
            if (t > 0 && tid < 64) {
                const int* f = flag1 + (size_t)(t - 1) * 64 + tid;
                while (!__all(aloadi(f) != 0)) {}
            }
            __syncthreads();  // A
            if (tid < 32) gxl[tid] = gxv;
            if (t > 0) {
                const float* hp = h1buf + ((t - 1) & 1) * 512;
                xl[tid] = aload(hp + tid);
                xl[tid + 256] = aload(hp + tid + 256);
            } else {
                xl[tid] = 0.f; xl[tid + 256] = 0.f;
            }
            __syncthreads();  // B
            float acc = 0.f;
#pragma unroll
            for (int q = 0; q < 64; q++) acc += w[q] * xl[p * 64 + q];
            part[p][r] = acc;
            __syncthreads();  // C
            if (tid < 8) {
                float s0 = gxl[tid], s1 = gxl[8 + tid], s2 = gxl[16 + tid], s3 = gxl[24 + tid];
#pragma unroll
                for (int pp = 0; pp < 8; pp++) {
                    s0 += part[pp][tid];
                    s1 += part[pp][8 + tid];
                    s2 += part[pp][16 + tid];
                    s3 += part[pp][24 + tid];
                }
                float ig = sigf(s0), fg = sigf(s1), gg = tanhf(s2), og = sigf(s3);
                float c = fg * cstate + ig * gg;
                cstate = c;
                float h = og * tanhf(c);
                astore(h1buf + (t & 1) * 512 + jb + tid, h);
                astore(h1seq + (size_t)t * 512 + jb + tid, lrelu(h));
            }
            asm volatile("s_waitcnt vmcnt(0)" ::: "memory");
            if (tid == 0) astorei(flag1 + (size_t)t * 64 + wg, 1);
        }
    } else {
        // ---------------- LSTM2: H=256, pipelined 1 step behind ----------------
        const int k = wg - 64, jb = k * 8;
        const int grow = (r >> 3) * 256 + jb + (r & 7);
        float wi[64], wh[32];
#pragma unroll
        for (int q = 0; q < 64; q++) wi[q] = Wih2[(size_t)grow * 512 + p * 64 + q];
#pragma unroll
        for (int q = 0; q < 32; q++) wh[q] = Whh2[(size_t)grow * 256 + p * 32 + q];
        float bs[4];
        if (tid < 8) {
#pragma unroll
            for (int g = 0; g < 4; g++) {
                int row = g * 256 + jb + tid;
                bs[g] = bih2[row] + bhh2[row];
            }
        }
        float cstate = 0.f;

        for (int t = 0; t < 4096; ++t) {
            if (tid < 64) {
                const int* f1 = flag1 + (size_t)t * 64 + tid;
                const int* f2 = flag2 + (size_t)(t - 1) * 32 + (tid & 31);
                while (true) {
                    int a = aloadi(f1);
                    int b = (t > 0) ? aloadi(f2) : 1;
                    if (__all((a != 0) & (b != 0))) break;
                }
            }
            __syncthreads();  // A
            {
                const float* xp = h1seq + (size_t)t * 512;
                xl[tid] = aload(xp + tid);
                xl[tid + 256] = aload(xp + tid + 256);
            }
            hl[tid] = (t == 0) ? 0.f : aload(h2buf + ((t - 1) & 1) * 256 + tid);
            __syncthreads();  // B
            float acc = 0.f;
#pragma unroll
            for (int q = 0; q < 64; q++) acc += wi[q] * xl[p * 64 + q];
#pragma unroll
            for (int q = 0; q < 32; q++) acc += wh[q] * hl[p * 32 + q];
            part[p][r] = acc;
            __syncthreads();  // C
            if (tid < 8) {
                float s0 = bs[0], s1 = bs[1], s2 = bs[2], s3 = bs[3];
#pragma unroll
                for (int pp = 0; pp < 8; pp++) {
                    s0 += part[pp][tid];
                    s1 += part[pp][8 + tid];
                    s2 += part[pp][16 + tid];
                    s3 += part[pp][24 + tid];
                }
                float ig = sigf(s0), fg = sigf(s1), gg = tanhf(s2), og = sigf(s3);
                float c = fg * cstate + ig * gg;
                cstate = c;
                float h = og * tanhf(c);
                astore(h2buf + (t & 1) * 256 + jb + tid, h);
                h2seq[(size_t)t * 256 + jb + tid] = lrelu(h);
            }
            asm volatile("s_waitcnt vmcnt(0)" ::: "memory");
            if (tid == 0) astorei(flag2 + (size_t)t * 32 + k, 1);
        }
    }
}

// ---------------- GCN edge scatter: y[dst] += ew * m[src] ----------------------
__global__ void gcn_scatter(const float* __restrict__ m, const int* __restrict__ ei,
                            const float* __restrict__ ew, float* __restrict__ y,
                            int shift, int nE)
{
    int idx = blockIdx.x * 256 + threadIdx.x;
    int e = idx >> shift;
    if (e >= nE) return;
    int C = 1 << shift;
    int ch = idx & (C - 1);
    int s = ei[e], d = ei[nE + e];
    atomicAdd(&y[(size_t)d * C + ch], ew[e] * m[(size_t)s * C + ch]);
}

// ---------------- BN (training-mode batch stats) -------------------------------
__global__ __launch_bounds__(256) void bn_stats(
    const float* __restrict__ x, const float* __restrict__ gamma,
    const float* __restrict__ beta, float* __restrict__ scale,
    float* __restrict__ shift, int Nn, int C)
{
    int ch = blockIdx.x;
    float s = 0.f, s2 = 0.f;
    for (int n = threadIdx.x; n < Nn; n += 256) {
        float v = x[(size_t)n * C + ch];
        s += v; s2 += v * v;
    }
    __shared__ float rs[256], rq[256];
    rs[threadIdx.x] = s; rq[threadIdx.x] = s2;
    __syncthreads();
    for (int o = 128; o > 0; o >>= 1) {
        if (threadIdx.x < o) {
            rs[threadIdx.x] += rs[threadIdx.x + o];
            rq[threadIdx.x] += rq[threadIdx.x + o];
        }
        __syncthreads();
    }
    if (threadIdx.x == 0) {
        float mean = rs[0] / Nn;
        float var = rq[0] / Nn - mean * mean;
        float inv = rsqrtf(var + 1e-5f);
        float sc = gamma[ch] * inv;
        scale[ch] = sc;
        shift[ch] = beta[ch] - mean * sc;
    }
}

__global__ void bn_apply(const float* __restrict__ x, const float* __restrict__ scale,
                         const float* __restrict__ shift, float* __restrict__ z,
                         int mask, int total)
{
    int idx = blockIdx.x * 256 + threadIdx.x;
    if (idx >= total) return;
    int ch = idx & mask;
    z[idx] = lrelu(x[idx] * scale[ch] + shift[ch]);
}

// ---------------- global_add_pool via batch array ------------------------------
__global__ void pool_kernel(const float* __restrict__ z, const int* __restrict__ batch,
                            float* __restrict__ pooled, int total)
{
    int idx = blockIdx.x * 256 + threadIdx.x;
    if (idx >= total) return;
    int n = idx >> 5, ch = idx & 31;
    atomicAdd(&pooled[(size_t)batch[n] * 32 + ch], z[idx]);
}

// ---------------- final tiny MLP: 32 -> 16 -> 8 -> 2, one thread per graph -----
__global__ void mlp_kernel(const float* __restrict__ pooled,
                           const float* __restrict__ w2, const float* __restrict__ b2,
                           const float* __restrict__ w3, const float* __restrict__ b3,
                           const float* __restrict__ w4, const float* __restrict__ b4,
                           float* __restrict__ out)
{
    int g = blockIdx.x * 256 + threadIdx.x;
    if (g >= 512) return;
    float pbuf[32];
#pragma unroll
    for (int i = 0; i < 32; i++) pbuf[i] = pooled[g * 32 + i];
    float a[16];
#pragma unroll
    for (int j = 0; j < 16; j++) {
        float s = b2[j];
#pragma unroll
        for (int i = 0; i < 32; i++) s += w2[j * 32 + i] * pbuf[i];
        a[j] = lrelu(s);
    }
    float c8[8];
#pragma unroll
    for (int j = 0; j < 8; j++) {
        float s = b3[j];
#pragma unroll
        for (int i = 0; i < 16; i++) s += w3[j * 16 + i] * a[i];
        c8[j] = lrelu(s);
    }
#pragma unroll
    for (int j = 0; j < 2; j++) {
        float s = b4[j];
#pragma unroll
        for (int i = 0; i < 8; i++) s += w4[j * 8 + i] * c8[i];
        out[g * 2 + j] = lrelu(s);
    }
}

extern "C" void kernel_launch(void* const* d_in, const int* in_sizes, int n_in,
                              void* d_out, int out_size, void* d_ws, size_t ws_size,
                              hipStream_t stream)
{
    (void)in_sizes; (void)n_in; (void)out_size; (void)ws_size;
    const float* x      = (const float*)d_in[0];
    const int*   ei     = (const int*)d_in[1];
    const float* ew     = (const float*)d_in[2];
    const int*   batch  = (const int*)d_in[3];
    const float* W_ih1  = (const float*)d_in[4];
    const float* W_hh1  = (const float*)d_in[5];
    const float* b_ih1  = (const float*)d_in[6];
    const float* b_hh1  = (const float*)d_in[7];
    const float* W_ih2  = (const float*)d_in[8];
    const float* W_hh2  = (const float*)d_in[9];
    const float* b_ih2  = (const float*)d_in[10];
    const float* b_hh2  = (const float*)d_in[11];
    const float* fc1_w  = (const float*)d_in[12];
    const float* fc1_b  = (const float*)d_in[13];
    const float* gcn1_w = (const float*)d_in[14];
    const float* bn1_g  = (const float*)d_in[16];
    const float* bn1_b  = (const float*)d_in[17];
    const float* gcn2_w = (const float*)d_in[18];
    const float* bn2_g  = (const float*)d_in[20];
    const float* bn2_b  = (const float*)d_in[21];
    const float* fc2_w  = (const float*)d_in[22];
    const float* fc2_b  = (const float*)d_in[23];
    const float* fc3_w  = (const float*)d_in[24];
    const float* fc3_b  = (const float*)d_in[25];
    const float* fc4_w  = (const float*)d_in[26];
    const float* fc4_b  = (const float*)d_in[27];
    float* out = (float*)d_out;

    // -------- workspace layout (fp32 elements) --------
    float* ws    = (float*)d_ws;
    float* gx1   = ws;                                   // 4096*2048 = 8M floats
    float* h1seq = gx1 + (size_t)4096 * 2048;            // 4096*512
    float* h2seq = h1seq + (size_t)4096 * 512;           // 4096*256
    float* h1buf = h2seq + (size_t)4096 * 256;           // 2*512
    float* h2buf = h1buf + 2 * 512;                      // 2*256
    float* scale1 = h2buf + 2 * 256;                     // 64
    float* shift1 = scale1 + 64;                         // 64
    float* scale2 = shift1 + 64;                         // 32
    float* shift2 = scale2 + 32;                         // 32
    int*   flag1 = (int*)(shift2 + 32);                  // 4096*64
    int*   flag2 = flag1 + (size_t)4096 * 64;            // 4096*32
    // buffers used only AFTER lstm_pipe — aliased into gx1's space:
    float* h3    = ws;                                   // 4096*128
    float* m1    = h3 + (size_t)4096 * 128;              // 4096*64
    float* y1    = m1 + (size_t)4096 * 64;               // 4096*64 (bn in-place)
    float* m2    = y1 + (size_t)4096 * 64;               // 4096*32
    float* y2    = m2 + (size_t)4096 * 32;               // 4096*32 (bn in-place)
    float* pooled = y2 + (size_t)4096 * 32;              // 512*32

    dim3 b256(256);

    hipMemsetAsync(flag1, 0, (size_t)4096 * 96 * sizeof(int), stream);

    // gx1 = x @ W_ih1^T + (b_ih1 + b_hh1)   [4096,2048]
    gemm_bias<false><<<dim3(2048 / 64, 4096 / 64), b256, 0, stream>>>(
        x, W_ih1, b_ih1, b_hh1, gx1, 4096, 2048, 1280);

    // both LSTM scans, pipelined (persistent, 96 WGs)
    lstm_pipe<<<96, b256, 0, stream>>>(gx1, W_hh1, W_ih2, W_hh2, b_ih2, b_hh2,
                                       h1seq, h2seq, h1buf, h2buf, flag1, flag2);

    // fc1 + lrelu  [4096,128]
    gemm_bias<true><<<dim3(128 / 64, 4096 / 64), b256, 0, stream>>>(
        h2seq, fc1_w, fc1_b, nullptr, h3, 4096, 128, 256);

    // gcn1 linear [4096,64]  (bias cancels in BN)
    gemm_bias<false><<<dim3(1, 4096 / 64), b256, 0, stream>>>(
        h3, gcn1_w, nullptr, nullptr, m1, 4096, 64, 128);
    hipMemsetAsync(y1, 0, (size_t)4096 * 64 * sizeof(float), stream);
    gcn_scatter<<<(32768 * 64) / 256, b256, 0, stream>>>(m1, ei, ew, y1, 6, 32768);
    bn_stats<<<64, b256, 0, stream>>>(y1, bn1_g, bn1_b, scale1, shift1, 4096, 64);
    bn_apply<<<(4096 * 64) / 256, b256, 0, stream>>>(y1, scale1, shift1, y1, 63, 4096 * 64);

    // gcn2 linear [4096,32]
    gemm_bias<false><<<dim3(1, 4096 / 64), b256, 0, stream>>>(
        y1, gcn2_w, nullptr, nullptr, m2, 4096, 32, 64);
    hipMemsetAsync(y2, 0, (size_t)4096 * 32 * sizeof(float), stream);
    gcn_scatter<<<(32768 * 32) / 256, b256, 0, stream>>>(m2, ei, ew, y2, 5, 32768);
    bn_stats<<<32, b256, 0, stream>>>(y2, bn2_g, bn2_b, scale2, shift2, 4096, 32);
    bn_apply<<<(4096 * 32) / 256, b256, 0, stream>>>(y2, scale2, shift2, y2, 31, 4096 * 32);

    // pool + MLP head
    hipMemsetAsync(pooled, 0, (size_t)512 * 32 * sizeof(float), stream);
    pool_kernel<<<(4096 * 32) / 256, b256, 0, stream>>>(y2, batch, pooled, 4096 * 32);
    mlp_kernel<<<2, b256, 0, stream>>>(pooled, fc2_w, fc2_b, fc3_w, fc3_b,
                                       fc4_w, fc4_b, out);
}

// Round 3
// 7743.677 us; speedup vs baseline: 5.3984x; 1.8267x over previous
//
#include <hip/hip_runtime.h>
#include <math.h>

#define AGENT __HIP_MEMORY_SCOPE_AGENT
typedef unsigned long long u64;

__device__ __forceinline__ float sigf(float x) { return 1.f / (1.f + __expf(-x)); }
__device__ __forceinline__ float lrelu(float x) { return x > 0.f ? x : 0.01f * x; }
__device__ __forceinline__ u64 aload64(const u64* p) {
    return __hip_atomic_load(p, __ATOMIC_RELAXED, AGENT);
}
__device__ __forceinline__ void astore64(u64* p, u64 v) {
    __hip_atomic_store(p, v, __ATOMIC_RELAXED, AGENT);
}

// ---------------- generic fp32 GEMM: C[m][n] = sum_k A[m][k]*B[n][k] + bias ----
template <bool LRELU>
__global__ __launch_bounds__(256) void gemm_bias(
    const float* __restrict__ A, const float* __restrict__ B,
    const float* __restrict__ bias1, const float* __restrict__ bias2,
    float* __restrict__ C, int M, int N, int K)
{
    __shared__ float As[16][68];
    __shared__ float Bs[16][68];
    const int tid = threadIdx.x;
    const int m0 = blockIdx.y * 64, n0 = blockIdx.x * 64;
    const int tm = tid >> 4, tn = tid & 15;
    const int lr = tid >> 2;
    const int lk = (tid & 3) * 4;
    float acc[4][4] = {};
    for (int k0 = 0; k0 < K; k0 += 16) {
        float4 av = make_float4(0.f, 0.f, 0.f, 0.f);
        if (m0 + lr < M) av = *(const float4*)&A[(size_t)(m0 + lr) * K + k0 + lk];
        As[lk + 0][lr] = av.x; As[lk + 1][lr] = av.y;
        As[lk + 2][lr] = av.z; As[lk + 3][lr] = av.w;
        float4 bv = make_float4(0.f, 0.f, 0.f, 0.f);
        if (n0 + lr < N) bv = *(const float4*)&B[(size_t)(n0 + lr) * K + k0 + lk];
        Bs[lk + 0][lr] = bv.x; Bs[lk + 1][lr] = bv.y;
        Bs[lk + 2][lr] = bv.z; Bs[lk + 3][lr] = bv.w;
        __syncthreads();
#pragma unroll
        for (int kk = 0; kk < 16; kk++) {
            float a[4], b[4];
#pragma unroll
            for (int i = 0; i < 4; i++) a[i] = As[kk][tm * 4 + i];
#pragma unroll
            for (int j = 0; j < 4; j++) b[j] = Bs[kk][tn * 4 + j];
#pragma unroll
            for (int i = 0; i < 4; i++)
#pragma unroll
                for (int j = 0; j < 4; j++) acc[i][j] += a[i] * b[j];
        }
        __syncthreads();
    }
#pragma unroll
    for (int i = 0; i < 4; i++) {
#pragma unroll
        for (int j = 0; j < 4; j++) {
            int mm = m0 + tm * 4 + i, nn = n0 + tn * 4 + j;
            if (mm < M && nn < N) {
                float v = acc[i][j];
                if (bias1) v += bias1[nn];
                if (bias2) v += bias2[nn];
                if (LRELU) v = lrelu(v);
                C[(size_t)mm * N + nn] = v;
            }
        }
    }
}

// ---------------- persistent pipelined LSTM1+LSTM2 scan ------------------------
// Tagged-data signaling: h(t) element j published as (t+1)<<32 | bits(h) into a
// full-sequence u64 buffer. Consumers poll the data word itself until the tag
// matches — one coherence round trip, no flags, no fences, no drains. Slots are
// unique per timestep so tags only move forward: race-free and deadlock-free.
__global__ __launch_bounds__(256) void lstm_pipe(
    const float* __restrict__ gx1, const float* __restrict__ Whh1,
    const float* __restrict__ Wih2, const float* __restrict__ Whh2,
    const float* __restrict__ bih2, const float* __restrict__ bhh2,
    u64* __restrict__ h1pub, u64* __restrict__ h2pub,
    float* __restrict__ h2seq)
{
    const int wg = blockIdx.x, tid = threadIdx.x;
    const int r = tid & 31, p = tid >> 5;
    __shared__ float xl[512];
    __shared__ float hl[256];
    __shared__ float part[8][32];

    if (wg < 64) {
        // ---------------- LSTM1: H=512, owns h[jb..jb+8) ----------------
        const int jb = wg * 8;
        const int grow = (r >> 3) * 512 + jb + (r & 7);
        float w[64];
#pragma unroll
        for (int q = 0; q < 64; q++) w[q] = Whh1[(size_t)grow * 512 + p * 64 + q];
        float cstate = 0.f;  // live in wave-0 lanes < 8

        for (int t = 0; t < 4096; ++t) {
            // prefetch gx for this step's 32 gate rows (independent of poll)
            float gxv = 0.f;
            if (tid < 32) gxv = gx1[(size_t)t * 2048 + (tid >> 3) * 512 + jb + (tid & 7)];
            if (t > 0) {
                const u64* base = h1pub + (size_t)(t - 1) * 512;
                const u64 want = (u64)t;
                u64 a = aload64(base + 2 * tid);
                u64 b = aload64(base + 2 * tid + 1);
                while ((a >> 32) != want || (b >> 32) != want) {
                    if ((a >> 32) != want) a = aload64(base + 2 * tid);
                    if ((b >> 32) != want) b = aload64(base + 2 * tid + 1);
                }
                xl[2 * tid]     = __uint_as_float((unsigned)a);
                xl[2 * tid + 1] = __uint_as_float((unsigned)b);
            } else {
                xl[2 * tid] = 0.f; xl[2 * tid + 1] = 0.f;
            }
            __syncthreads();  // xl ready
            float acc = 0.f;
#pragma unroll
            for (int q = 0; q < 64; q++) acc += w[q] * xl[p * 64 + q];
            part[p][r] = acc;
            __syncthreads();  // part ready
            if (tid < 32) {
                float s = gxv;
#pragma unroll
                for (int pp = 0; pp < 8; pp++) s += part[pp][tid];
                const int g = tid >> 3;
                float act = (g == 2) ? tanhf(s) : sigf(s);
                const int e = tid & 7;
                float vi = __shfl(act, e, 64);
                float vf = __shfl(act, e + 8, 64);
                float vg = __shfl(act, e + 16, 64);
                float vo = __shfl(act, e + 24, 64);
                if (tid < 8) {
                    float c = vf * cstate + vi * vg;
                    cstate = c;
                    float h = vo * tanhf(c);
                    astore64(h1pub + (size_t)t * 512 + jb + tid,
                             ((u64)(t + 1) << 32) | (u64)__float_as_uint(h));
                }
            }
        }
    } else {
        // ---------------- LSTM2: H=256, pipelined 1 step behind ----------------
        const int k = wg - 64, jb = k * 8;
        const int grow = (r >> 3) * 256 + jb + (r & 7);
        float wi[64], wh[32];
#pragma unroll
        for (int q = 0; q < 64; q++) wi[q] = Wih2[(size_t)grow * 512 + p * 64 + q];
#pragma unroll
        for (int q = 0; q < 32; q++) wh[q] = Whh2[(size_t)grow * 256 + p * 32 + q];
        float bs = 0.f;
        if (tid < 32) {
            int row = (tid >> 3) * 256 + jb + (tid & 7);
            bs = bih2[row] + bhh2[row];
        }
        float cstate = 0.f;

        for (int t = 0; t < 4096; ++t) {
            {
                const u64* b1 = h1pub + (size_t)t * 512;
                const u64* b2 = h2pub + (size_t)(t - 1) * 256;
                const u64 want1 = (u64)(t + 1);
                const u64 want2 = (u64)t;
                u64 a = aload64(b1 + 2 * tid);
                u64 b = aload64(b1 + 2 * tid + 1);
                u64 c = (t > 0) ? aload64(b2 + tid) : (want2 << 32);
                while ((a >> 32) != want1 || (b >> 32) != want1 || (c >> 32) != want2) {
                    if ((a >> 32) != want1) a = aload64(b1 + 2 * tid);
                    if ((b >> 32) != want1) b = aload64(b1 + 2 * tid + 1);
                    if ((c >> 32) != want2) c = aload64(b2 + tid);
                }
                xl[2 * tid]     = lrelu(__uint_as_float((unsigned)a));
                xl[2 * tid + 1] = lrelu(__uint_as_float((unsigned)b));
                hl[tid] = (t > 0) ? __uint_as_float((unsigned)c) : 0.f;
            }
            __syncthreads();
            float acc = 0.f;
#pragma unroll
            for (int q = 0; q < 64; q++) acc += wi[q] * xl[p * 64 + q];
#pragma unroll
            for (int q = 0; q < 32; q++) acc += wh[q] * hl[p * 32 + q];
            part[p][r] = acc;
            __syncthreads();
            if (tid < 32) {
                float s = bs;
#pragma unroll
                for (int pp = 0; pp < 8; pp++) s += part[pp][tid];
                const int g = tid >> 3;
                float act = (g == 2) ? tanhf(s) : sigf(s);
                const int e = tid & 7;
                float vi = __shfl(act, e, 64);
                float vf = __shfl(act, e + 8, 64);
                float vg = __shfl(act, e + 16, 64);
                float vo = __shfl(act, e + 24, 64);
                if (tid < 8) {
                    float c = vf * cstate + vi * vg;
                    cstate = c;
                    float h = vo * tanhf(c);
                    astore64(h2pub + (size_t)t * 256 + jb + tid,
                             ((u64)(t + 1) << 32) | (u64)__float_as_uint(h));
                    h2seq[(size_t)t * 256 + jb + tid] = lrelu(h);  // off critical path
                }
            }
        }
    }
}

// ---------------- GCN edge scatter: y[dst] += ew * m[src] ----------------------
__global__ void gcn_scatter(const float* __restrict__ m, const int* __restrict__ ei,
                            const float* __restrict__ ew, float* __restrict__ y,
                            int shift, int nE)
{
    int idx = blockIdx.x * 256 + threadIdx.x;
    int e = idx >> shift;
    if (e >= nE) return;
    int C = 1 << shift;
    int ch = idx & (C - 1);
    int s = ei[e], d = ei[nE + e];
    atomicAdd(&y[(size_t)d * C + ch], ew[e] * m[(size_t)s * C + ch]);
}

// ---------------- BN (training-mode batch stats) -------------------------------
__global__ __launch_bounds__(256) void bn_stats(
    const float* __restrict__ x, const float* __restrict__ gamma,
    const float* __restrict__ beta, float* __restrict__ scale,
    float* __restrict__ shift, int Nn, int C)
{
    int ch = blockIdx.x;
    float s = 0.f, s2 = 0.f;
    for (int n = threadIdx.x; n < Nn; n += 256) {
        float v = x[(size_t)n * C + ch];
        s += v; s2 += v * v;
    }
    __shared__ float rs[256], rq[256];
    rs[threadIdx.x] = s; rq[threadIdx.x] = s2;
    __syncthreads();
    for (int o = 128; o > 0; o >>= 1) {
        if (threadIdx.x < o) {
            rs[threadIdx.x] += rs[threadIdx.x + o];
            rq[threadIdx.x] += rq[threadIdx.x + o];
        }
        __syncthreads();
    }
    if (threadIdx.x == 0) {
        float mean = rs[0] / Nn;
        float var = rq[0] / Nn - mean * mean;
        float inv = rsqrtf(var + 1e-5f);
        float sc = gamma[ch] * inv;
        scale[ch] = sc;
        shift[ch] = beta[ch] - mean * sc;
    }
}

__global__ void bn_apply(const float* __restrict__ x, const float* __restrict__ scale,
                         const float* __restrict__ shift, float* __restrict__ z,
                         int mask, int total)
{
    int idx = blockIdx.x * 256 + threadIdx.x;
    if (idx >= total) return;
    int ch = idx & mask;
    z[idx] = lrelu(x[idx] * scale[ch] + shift[ch]);
}

// ---------------- global_add_pool via batch array ------------------------------
__global__ void pool_kernel(const float* __restrict__ z, const int* __restrict__ batch,
                            float* __restrict__ pooled, int total)
{
    int idx = blockIdx.x * 256 + threadIdx.x;
    if (idx >= total) return;
    int n = idx >> 5, ch = idx & 31;
    atomicAdd(&pooled[(size_t)batch[n] * 32 + ch], z[idx]);
}

// ---------------- final tiny MLP: 32 -> 16 -> 8 -> 2, one thread per graph -----
__global__ void mlp_kernel(const float* __restrict__ pooled,
                           const float* __restrict__ w2, const float* __restrict__ b2,
                           const float* __restrict__ w3, const float* __restrict__ b3,
                           const float* __restrict__ w4, const float* __restrict__ b4,
                           float* __restrict__ out)
{
    int g = blockIdx.x * 256 + threadIdx.x;
    if (g >= 512) return;
    float pbuf[32];
#pragma unroll
    for (int i = 0; i < 32; i++) pbuf[i] = pooled[g * 32 + i];
    float a[16];
#pragma unroll
    for (int j = 0; j < 16; j++) {
        float s = b2[j];
#pragma unroll
        for (int i = 0; i < 32; i++) s += w2[j * 32 + i] * pbuf[i];
        a[j] = lrelu(s);
    }
    float c8[8];
#pragma unroll
    for (int j = 0; j < 8; j++) {
        float s = b3[j];
#pragma unroll
        for (int i = 0; i < 16; i++) s += w3[j * 16 + i] * a[i];
        c8[j] = lrelu(s);
    }
#pragma unroll
    for (int j = 0; j < 2; j++) {
        float s = b4[j];
#pragma unroll
        for (int i = 0; i < 8; i++) s += w4[j * 8 + i] * c8[i];
        out[g * 2 + j] = lrelu(s);
    }
}

extern "C" void kernel_launch(void* const* d_in, const int* in_sizes, int n_in,
                              void* d_out, int out_size, void* d_ws, size_t ws_size,
                              hipStream_t stream)
{
    (void)in_sizes; (void)n_in; (void)out_size; (void)ws_size;
    const float* x      = (const float*)d_in[0];
    const int*   ei     = (const int*)d_in[1];
    const float* ew     = (const float*)d_in[2];
    const int*   batch  = (const int*)d_in[3];
    const float* W_ih1  = (const float*)d_in[4];
    const float* W_hh1  = (const float*)d_in[5];
    const float* b_ih1  = (const float*)d_in[6];
    const float* b_hh1  = (const float*)d_in[7];
    const float* W_ih2  = (const float*)d_in[8];
    const float* W_hh2  = (const float*)d_in[9];
    const float* b_ih2  = (const float*)d_in[10];
    const float* b_hh2  = (const float*)d_in[11];
    const float* fc1_w  = (const float*)d_in[12];
    const float* fc1_b  = (const float*)d_in[13];
    const float* gcn1_w = (const float*)d_in[14];
    const float* bn1_g  = (const float*)d_in[16];
    const float* bn1_b  = (const float*)d_in[17];
    const float* gcn2_w = (const float*)d_in[18];
    const float* bn2_g  = (const float*)d_in[20];
    const float* bn2_b  = (const float*)d_in[21];
    const float* fc2_w  = (const float*)d_in[22];
    const float* fc2_b  = (const float*)d_in[23];
    const float* fc3_w  = (const float*)d_in[24];
    const float* fc3_b  = (const float*)d_in[25];
    const float* fc4_w  = (const float*)d_in[26];
    const float* fc4_b  = (const float*)d_in[27];
    float* out = (float*)d_out;

    // -------- workspace layout --------
    float* ws    = (float*)d_ws;
    float* gx1   = ws;                                   // 4096*2048 f32 (32MB)
    u64*   h1pub = (u64*)(gx1 + (size_t)4096 * 2048);    // 4096*512 u64 (16MB)
    u64*   h2pub = h1pub + (size_t)4096 * 512;           // 4096*256 u64 (8MB)
    float* h2seq = (float*)(h2pub + (size_t)4096 * 256); // 4096*256 f32 (4MB)
    float* scale1 = h2seq + (size_t)4096 * 256;          // 64
    float* shift1 = scale1 + 64;                         // 64
    float* scale2 = shift1 + 64;                         // 32
    float* shift2 = scale2 + 32;                         // 32
    // buffers used only AFTER lstm_pipe — aliased into gx1's space:
    float* h3    = ws;                                   // 4096*128
    float* m1    = h3 + (size_t)4096 * 128;              // 4096*64
    float* y1    = m1 + (size_t)4096 * 64;               // 4096*64 (bn in-place)
    float* m2    = y1 + (size_t)4096 * 64;               // 4096*32
    float* y2    = m2 + (size_t)4096 * 32;               // 4096*32 (bn in-place)
    float* pooled = y2 + (size_t)4096 * 32;              // 512*32

    dim3 b256(256);

    // fresh tags every launch (no cross-call state)
    hipMemsetAsync(h1pub, 0, (size_t)4096 * 768 * sizeof(u64), stream);

    // gx1 = x @ W_ih1^T + (b_ih1 + b_hh1)   [4096,2048]
    gemm_bias<false><<<dim3(2048 / 64, 4096 / 64), b256, 0, stream>>>(
        x, W_ih1, b_ih1, b_hh1, gx1, 4096, 2048, 1280);

    // both LSTM scans, pipelined (persistent, 96 WGs)
    lstm_pipe<<<96, b256, 0, stream>>>(gx1, W_hh1, W_ih2, W_hh2, b_ih2, b_hh2,
                                       h1pub, h2pub, h2seq);

    // fc1 + lrelu  [4096,128]
    gemm_bias<true><<<dim3(128 / 64, 4096 / 64), b256, 0, stream>>>(
        h2seq, fc1_w, fc1_b, nullptr, h3, 4096, 128, 256);

    // gcn1 linear [4096,64]  (bias cancels in BN)
    gemm_bias<false><<<dim3(1, 4096 / 64), b256, 0, stream>>>(
        h3, gcn1_w, nullptr, nullptr, m1, 4096, 64, 128);
    hipMemsetAsync(y1, 0, (size_t)4096 * 64 * sizeof(float), stream);
    gcn_scatter<<<(32768 * 64) / 256, b256, 0, stream>>>(m1, ei, ew, y1, 6, 32768);
    bn_stats<<<64, b256, 0, stream>>>(y1, bn1_g, bn1_b, scale1, shift1, 4096, 64);
    bn_apply<<<(4096 * 64) / 256, b256, 0, stream>>>(y1, scale1, shift1, y1, 63, 4096 * 64);

    // gcn2 linear [4096,32]
    gemm_bias<false><<<dim3(1, 4096 / 64), b256, 0, stream>>>(
        y1, gcn2_w, nullptr, nullptr, m2, 4096, 32, 64);
    hipMemsetAsync(y2, 0, (size_t)4096 * 32 * sizeof(float), stream);
    gcn_scatter<<<(32768 * 32) / 256, b256, 0, stream>>>(m2, ei, ew, y2, 5, 32768);
    bn_stats<<<32, b256, 0, stream>>>(y2, bn2_g, bn2_b, scale2, shift2, 4096, 32);
    bn_apply<<<(4096 * 32) / 256, b256, 0, stream>>>(y2, scale2, shift2, y2, 31, 4096 * 32);

    // pool + MLP head
    hipMemsetAsync(pooled, 0, (size_t)512 * 32 * sizeof(float), stream);
    pool_kernel<<<(4096 * 32) / 256, b256, 0, stream>>>(y2, batch, pooled, 4096 * 32);
    mlp_kernel<<<2, b256, 0, stream>>>(pooled, fc2_w, fc2_b, fc3_w, fc3_b,
                                       fc4_w, fc4_b, out);
}